// Round 3
// baseline (315.992 us; speedup 1.0000x reference)
//
#include <hip/hip_runtime.h>
#include <math.h>

#define B_ 32
#define D_ 16
#define T_ 1024
#define P_ 64
#define L_ 32
#define XSTR 20            // floats per column row: 16 x + x2 + pad to 80 B (16B-aligned tiles)
#define TILE 128           // columns per LDS tile
#define NTILE (T_ / TILE)
#define BIGV 1e30f

typedef float v2f __attribute__((ext_vector_type(2)));

// ---- DPP helpers -----------------------------------------------------------
template<int CTRL, int ROW_MASK, bool BC>
__device__ __forceinline__ float dpp_mov(float old_, float src) {
  int o = __builtin_bit_cast(int, old_);
  int s = __builtin_bit_cast(int, src);
  int r = __builtin_amdgcn_update_dpp(o, s, CTRL, ROW_MASK, 0xf, BC);
  return __builtin_bit_cast(float, r);
}

// Inclusive prefix-sum over each 32-lane half (0-fill via bound_ctrl -> fused v_add_f32_dpp).
__device__ __forceinline__ float scan_sum32(float v) {
  v += dpp_mov<0x111, 0xf, true>(0.f, v);   // row_shr:1
  v += dpp_mov<0x112, 0xf, true>(0.f, v);   // row_shr:2
  v += dpp_mov<0x114, 0xf, true>(0.f, v);   // row_shr:4
  v += dpp_mov<0x118, 0xf, true>(0.f, v);   // row_shr:8
  v += dpp_mov<0x142, 0xa, false>(0.f, v);  // row_bcast15 -> rows 1,3
  return v;
}

// Inclusive prefix-min over each 32-lane half. Invalid/masked lanes get old=v,
// and min(v,v)=v is the identity -> no BIG constant needed.
__device__ __forceinline__ float scan_min32(float v) {
  v = fminf(v, dpp_mov<0x111, 0xf, false>(v, v));
  v = fminf(v, dpp_mov<0x112, 0xf, false>(v, v));
  v = fminf(v, dpp_mov<0x114, 0xf, false>(v, v));
  v = fminf(v, dpp_mov<0x118, 0xf, false>(v, v));
  v = fminf(v, dpp_mov<0x142, 0xa, false>(v, v));
  return v;
}

// ---- transpose: x[b][d][t] -> xT[b][t][XSTR] rows (x[0..15], x2 at [16]) ---
__global__ void dtw_transpose(const float* __restrict__ x,
                              float* __restrict__ xT) {
  int gid = blockIdx.x * blockDim.x + threadIdx.x;   // 0 .. B*T-1
  if (gid >= B_ * T_) return;
  int b = gid >> 10;          // / T_
  int j = gid & (T_ - 1);
  float v[D_];
  float s = 0.f;
#pragma unroll
  for (int d = 0; d < D_; ++d) {
    v[d] = x[((size_t)(b * D_ + d)) * T_ + j];       // coalesced over j
    s = fmaf(v[d], v[d], s);
  }
  float* row = xT + (size_t)gid * XSTR;
  float4* dst = (float4*)row;
#pragma unroll
  for (int q = 0; q < 4; ++q)
    dst[q] = make_float4(v[4*q], v[4*q+1], v[4*q+2], v[4*q+3]);
  row[16] = s;
}

// ---- main DTW kernel -------------------------------------------------------
// Block = (b, 8 patterns), 256 threads; 32 lanes = pattern axis L.
// x columns flow: global -> (regs) -> LDS double-buffer (1 barrier / 128 cols)
//               -> distance-2 register prefetch (named scalars) -> VALU.
__global__ __launch_bounds__(256) void dtw_kernel(
    const float* __restrict__ xT,     // [B][T][XSTR]
    const float* __restrict__ patts,  // [P][D][L]
    const float* __restrict__ wp,     // scalar
    float* __restrict__ out)          // [B][P][T]
{
  __shared__ float lds[2][TILE * XSTR];   // 2 x 10240 B

  const int tid = threadIdx.x;
  const int li  = tid & 31;
  const int grp = tid >> 5;
  const int b   = blockIdx.x >> 3;
  const int p   = ((blockIdx.x & 7) << 3) + grp;
  const float w = wp[0];

  // pattern fragment in registers, packed as float2 for v_pk_fma_f32
  v2f pd2[8];
  float p2 = 0.f;
#pragma unroll
  for (int d = 0; d < D_; ++d) {
    float t = patts[((size_t)p * D_ + d) * L_ + li];
    ((float*)pd2)[d] = t;
    p2 = fmaf(t, t, p2);
  }

  const float4* xg = (const float4*)(xT + (size_t)b * T_ * XSTR);  // 5 float4 / column
  float* orow = out + ((size_t)(b * P_ + p)) * T_;

  const int QT = TILE * XSTR / 4;   // 640 float4 per tile

  // ---- stage tile 0 into lds[0] ----
  float4 st0, st1, st2;
  st0 = xg[tid];
  st1 = xg[tid + 256];
  if (tid < QT - 512) st2 = xg[tid + 512];
  ((float4*)lds[0])[tid] = st0;
  ((float4*)lds[0])[tid + 256] = st1;
  if (tid < QT - 512) ((float4*)lds[0])[tid + 512] = st2;
  __syncthreads();

  float dcur = 0.f;   // finite init; j==0 result selected via uniform ?: below

  for (int t = 0; t < NTILE; ++t) {
    // issue global prefetch of tile t+1 (clamped; last iter redundant)
    const int tn = (t + 1 < NTILE) ? t + 1 : t;
    const float4* src = xg + (size_t)tn * QT;
    st0 = src[tid];
    st1 = src[tid + 256];
    if (tid < QT - 512) st2 = src[tid + 512];

    const float* buf = lds[t & 1];
    const int jbase = t * TILE;

    // distance-2 LDS register prefetch, named scalars only
    float4 a0, a1, a2, a3; float as;
    float4 c0, c1, c2, c3; float cs;
    {
      const float* cp = buf;
      a0 = *(const float4*)(cp);      a1 = *(const float4*)(cp + 4);
      a2 = *(const float4*)(cp + 8);  a3 = *(const float4*)(cp + 12);
      as = cp[16];
      cp = buf + XSTR;
      c0 = *(const float4*)(cp);      c1 = *(const float4*)(cp + 4);
      c2 = *(const float4*)(cp + 8);  c3 = *(const float4*)(cp + 12);
      cs = cp[16];
    }

    auto step = [&](int j, const float4& r0, const float4& r1,
                    const float4& r2, const float4& r3, float rs) {
      v2f q0 = {0.f, 0.f}, q1 = {0.f, 0.f};
      q0 = __builtin_elementwise_fma(*(const v2f*)&r0.x, pd2[0], q0);
      q1 = __builtin_elementwise_fma(*(const v2f*)&r0.z, pd2[1], q1);
      q0 = __builtin_elementwise_fma(*(const v2f*)&r1.x, pd2[2], q0);
      q1 = __builtin_elementwise_fma(*(const v2f*)&r1.z, pd2[3], q1);
      q0 = __builtin_elementwise_fma(*(const v2f*)&r2.x, pd2[4], q0);
      q1 = __builtin_elementwise_fma(*(const v2f*)&r2.z, pd2[5], q1);
      q0 = __builtin_elementwise_fma(*(const v2f*)&r3.x, pd2[6], q0);
      q1 = __builtin_elementwise_fma(*(const v2f*)&r3.z, pd2[7], q1);
      v2f qs = q0 + q1;
      float dot = qs.x + qs.y;
      float c = fmaf(-2.f, dot, rs + p2);

      float S = scan_sum32(c);
      // D[i-1, j-1]: wave_shr:1; lanes 0/32 fixed with dcur (min identity)
      float pu = dpp_mov<0x138, 0xf, false>(dcur, dcur);
      pu = (li == 0) ? dcur : pu;
      float mn = fminf(dcur, pu);
      float e  = fmaf(w, mn, c - S);
      float M  = scan_min32(e);
      dcur = S + ((j == 0) ? 0.f : M);   // j==0 column is pure cumsum
      if (li == 31) orow[j] = sqrtf(dcur);
    };

    auto ldcol = [&](int k, float4& r0, float4& r1, float4& r2, float4& r3,
                     float& rs) {
      const float* cp = buf + k * XSTR;
      r0 = *(const float4*)(cp);      r1 = *(const float4*)(cp + 4);
      r2 = *(const float4*)(cp + 8);  r3 = *(const float4*)(cp + 12);
      rs = cp[16];
    };

    for (int k = 0; k < TILE; k += 2) {
      step(jbase + k, a0, a1, a2, a3, as);
      {
        const int kn = (k + 2 < TILE) ? k + 2 : TILE - 1;
        ldcol(kn, a0, a1, a2, a3, as);
      }
      step(jbase + k + 1, c0, c1, c2, c3, cs);
      {
        const int km = (k + 3 < TILE) ? k + 3 : TILE - 1;
        ldcol(km, c0, c1, c2, c3, cs);
      }
    }

    // commit staged tile t+1 into the other LDS buffer
    float4* dstb = (float4*)lds[(t + 1) & 1];
    dstb[tid] = st0;
    dstb[tid + 256] = st1;
    if (tid < QT - 512) dstb[tid + 512] = st2;
    __syncthreads();
  }
}

extern "C" void kernel_launch(void* const* d_in, const int* in_sizes, int n_in,
                              void* d_out, int out_size, void* d_ws, size_t ws_size,
                              hipStream_t stream) {
  const float* x     = (const float*)d_in[0];
  const float* patts = (const float*)d_in[1];
  const float* w     = (const float*)d_in[2];
  float* out = (float*)d_out;

  float* xT = (float*)d_ws;                  // B*T*XSTR floats = 2.62 MB

  dtw_transpose<<<(B_ * T_ + 255) / 256, 256, 0, stream>>>(x, xT);
  dtw_kernel<<<B_ * (P_ / 8), 256, 0, stream>>>(xT, patts, w, out);
}

// Round 4
// 314.975 us; speedup vs baseline: 1.0032x; 1.0032x over previous
//
#include <hip/hip_runtime.h>
#include <math.h>

#define B_ 32
#define D_ 16
#define T_ 1024
#define P_ 64
#define L_ 32
#define XSTR 20            // floats per column row: 16 x + x2 + pad to 80 B
#define TILE 128           // columns per LDS tile
#define NTILE (T_ / TILE)
#define BIGV 1e30f

typedef float v2f __attribute__((ext_vector_type(2)));

// ---- DPP helpers -----------------------------------------------------------
template<int CTRL, int ROW_MASK, bool BC>
__device__ __forceinline__ float dpp_mov(float old_, float src) {
  int o = __builtin_bit_cast(int, old_);
  int s = __builtin_bit_cast(int, src);
  int r = __builtin_amdgcn_update_dpp(o, s, CTRL, ROW_MASK, 0xf, BC);
  return __builtin_bit_cast(float, r);
}

// Inclusive prefix-sum over each 32-lane half (0-fill -> fused v_add_f32_dpp).
__device__ __forceinline__ float scan_sum32(float v) {
  v += dpp_mov<0x111, 0xf, true>(0.f, v);   // row_shr:1
  v += dpp_mov<0x112, 0xf, true>(0.f, v);   // row_shr:2
  v += dpp_mov<0x114, 0xf, true>(0.f, v);   // row_shr:4
  v += dpp_mov<0x118, 0xf, true>(0.f, v);   // row_shr:8
  v += dpp_mov<0x142, 0xa, false>(0.f, v);  // row_bcast15 -> rows 1,3
  return v;
}

// Inclusive prefix-min over each 32-lane half (old=v; min(v,v)=v identity).
__device__ __forceinline__ float scan_min32(float v) {
  v = fminf(v, dpp_mov<0x111, 0xf, false>(v, v));
  v = fminf(v, dpp_mov<0x112, 0xf, false>(v, v));
  v = fminf(v, dpp_mov<0x114, 0xf, false>(v, v));
  v = fminf(v, dpp_mov<0x118, 0xf, false>(v, v));
  v = fminf(v, dpp_mov<0x142, 0xa, false>(v, v));
  return v;
}

// ---- transpose: x[b][d][t] -> xT[b][t][XSTR] rows (x[0..15], x2 at [16]) ---
__global__ void dtw_transpose(const float* __restrict__ x,
                              float* __restrict__ xT) {
  int gid = blockIdx.x * blockDim.x + threadIdx.x;   // 0 .. B*T-1
  if (gid >= B_ * T_) return;
  int b = gid >> 10;          // / T_
  int j = gid & (T_ - 1);
  float v[D_];
  float s = 0.f;
#pragma unroll
  for (int d = 0; d < D_; ++d) {
    v[d] = x[((size_t)(b * D_ + d)) * T_ + j];       // coalesced over j
    s = fmaf(v[d], v[d], s);
  }
  float* row = xT + (size_t)gid * XSTR;
  float4* dst = (float4*)row;
#pragma unroll
  for (int q = 0; q < 4; ++q)
    dst[q] = make_float4(v[4*q], v[4*q+1], v[4*q+2], v[4*q+3]);
  row[16] = s;
}

// ---- main DTW kernel -------------------------------------------------------
// Block = (b, 8 patterns), 256 threads; 32 lanes = pattern axis L.
// Grid is 256 blocks on 256 CUs -> structurally 1 wave/SIMD, so declare
// __launch_bounds__(256, 1): the full VGPR file (≈512) is available and the
// register pipeline below must NOT be collapsed by an occupancy-targeting
// allocator (VGPR=36 in R3 serialized every LDS read -> 120cyc stall/col).
__global__ __launch_bounds__(256, 1) void dtw_kernel(
    const float* __restrict__ xT,     // [B][T][XSTR]
    const float* __restrict__ patts,  // [P][D][L]
    const float* __restrict__ wp,     // scalar
    float* __restrict__ out)          // [B][P][T]
{
  __shared__ float lds[2][TILE * XSTR];   // 2 x 10240 B

  const int tid = threadIdx.x;
  const int li  = tid & 31;
  const int grp = tid >> 5;
  const int b   = blockIdx.x >> 3;
  const int p   = ((blockIdx.x & 7) << 3) + grp;
  const float w = wp[0];

  // pattern fragment in registers, packed as float2 for v_pk_fma_f32
  v2f pd2[8];
  float p2 = 0.f;
#pragma unroll
  for (int d = 0; d < D_; ++d) {
    float t = patts[((size_t)p * D_ + d) * L_ + li];
    ((float*)pd2)[d] = t;
    p2 = fmaf(t, t, p2);
  }

  const float4* xg = (const float4*)(xT + (size_t)b * T_ * XSTR);
  float* orow = out + ((size_t)(b * P_ + p)) * T_;

  const int QT = TILE * XSTR / 4;   // 640 float4 per tile

  // ---- stage tile 0 into lds[0] ----
  float4 st0, st1, st2;
  st0 = xg[tid];
  st1 = xg[tid + 256];
  if (tid < QT - 512) st2 = xg[tid + 512];
  ((float4*)lds[0])[tid] = st0;
  ((float4*)lds[0])[tid + 256] = st1;
  if (tid < QT - 512) ((float4*)lds[0])[tid + 512] = st2;
  __syncthreads();

  float dcur = 0.f;   // finite init; j==0 handled via uniform select below

  for (int t = 0; t < NTILE; ++t) {
    // issue global prefetch of tile t+1 (clamped; last iter redundant)
    const int tn = (t + 1 < NTILE) ? t + 1 : t;
    const float4* src = xg + (size_t)tn * QT;
    st0 = src[tid];
    st1 = src[tid + 256];
    if (tid < QT - 512) st2 = src[tid + 512];

    const float* buf = lds[t & 1];
    const int jbase = t * TILE;

    // distance-2 LDS register prefetch, named scalars only
    float4 a0, a1, a2, a3; float as;
    float4 c0, c1, c2, c3; float cs;
    {
      const float* cp = buf;
      a0 = *(const float4*)(cp);      a1 = *(const float4*)(cp + 4);
      a2 = *(const float4*)(cp + 8);  a3 = *(const float4*)(cp + 12);
      as = cp[16];
      cp = buf + XSTR;
      c0 = *(const float4*)(cp);      c1 = *(const float4*)(cp + 4);
      c2 = *(const float4*)(cp + 8);  c3 = *(const float4*)(cp + 12);
      cs = cp[16];
    }

    auto step = [&](int j, const float4& r0, const float4& r1,
                    const float4& r2, const float4& r3, float rs) {
      v2f q0 = {0.f, 0.f}, q1 = {0.f, 0.f};
      q0 = __builtin_elementwise_fma(*(const v2f*)&r0.x, pd2[0], q0);
      q1 = __builtin_elementwise_fma(*(const v2f*)&r0.z, pd2[1], q1);
      q0 = __builtin_elementwise_fma(*(const v2f*)&r1.x, pd2[2], q0);
      q1 = __builtin_elementwise_fma(*(const v2f*)&r1.z, pd2[3], q1);
      q0 = __builtin_elementwise_fma(*(const v2f*)&r2.x, pd2[4], q0);
      q1 = __builtin_elementwise_fma(*(const v2f*)&r2.z, pd2[5], q1);
      q0 = __builtin_elementwise_fma(*(const v2f*)&r3.x, pd2[6], q0);
      q1 = __builtin_elementwise_fma(*(const v2f*)&r3.z, pd2[7], q1);
      v2f qs = q0 + q1;
      float dot = qs.x + qs.y;
      float c = fmaf(-2.f, dot, rs + p2);

      float S = scan_sum32(c);
      // D[i-1, j-1]: wave_shr:1; lanes 0/32 fixed with dcur (min identity)
      float pu = dpp_mov<0x138, 0xf, false>(dcur, dcur);
      pu = (li == 0) ? dcur : pu;
      float mn = fminf(dcur, pu);
      float e  = fmaf(w, mn, c - S);
      float M  = scan_min32(e);
      dcur = S + ((j == 0) ? 0.f : M);   // j==0 column is pure cumsum
      if (li == 31) orow[j] = sqrtf(dcur);
    };

    auto ldcol = [&](int k, float4& r0, float4& r1, float4& r2, float4& r3,
                     float& rs) {
      const float* cp = buf + k * XSTR;
      r0 = *(const float4*)(cp);      r1 = *(const float4*)(cp + 4);
      r2 = *(const float4*)(cp + 8);  r3 = *(const float4*)(cp + 12);
      rs = cp[16];
    };

    for (int k = 0; k < TILE; k += 2) {
      step(jbase + k, a0, a1, a2, a3, as);
      {
        const int kn = (k + 2 < TILE) ? k + 2 : TILE - 1;
        ldcol(kn, a0, a1, a2, a3, as);
      }
      step(jbase + k + 1, c0, c1, c2, c3, cs);
      {
        const int km = (k + 3 < TILE) ? k + 3 : TILE - 1;
        ldcol(km, c0, c1, c2, c3, cs);
      }
    }

    // commit staged tile t+1 into the other LDS buffer
    float4* dstb = (float4*)lds[(t + 1) & 1];
    dstb[tid] = st0;
    dstb[tid + 256] = st1;
    if (tid < QT - 512) dstb[tid + 512] = st2;
    __syncthreads();
  }
}

extern "C" void kernel_launch(void* const* d_in, const int* in_sizes, int n_in,
                              void* d_out, int out_size, void* d_ws, size_t ws_size,
                              hipStream_t stream) {
  const float* x     = (const float*)d_in[0];
  const float* patts = (const float*)d_in[1];
  const float* w     = (const float*)d_in[2];
  float* out = (float*)d_out;

  float* xT = (float*)d_ws;                  // B*T*XSTR floats = 2.62 MB

  dtw_transpose<<<(B_ * T_ + 255) / 256, 256, 0, stream>>>(x, xT);
  dtw_kernel<<<B_ * (P_ / 8), 256, 0, stream>>>(xT, patts, w, out);
}